// Round 1
// baseline (713.874 us; speedup 1.0000x reference)
//
#include <hip/hip_runtime.h>
#include <cmath>

// Problem constants
#define BB 64
#define TT 128
#define SS 512
#define EE 1024
#define DD 512
#define NEG_INF_F (-1.0e10f)

// GEMM tiling
#define BM 64
#define BN 64
#define BK 16

// ---------------------------------------------------------------------------
// K1: decW[m,e] = sum_d dec[m,d] * W_attn[e,d]
//     A = dec [8192, 512] row-major; Bt = W_attn [1024, 512] row-major (NT)
// ---------------------------------------------------------------------------
__global__ __launch_bounds__(256) void k_decw(const float* __restrict__ A,
                                              const float* __restrict__ Bt,
                                              float* __restrict__ C) {
    __shared__ float as[BK][BM + 4];
    __shared__ float bs[BK][BN + 4];
    const int tid = threadIdx.x;
    const int tx = tid & 15, ty = tid >> 4;
    const int bm = blockIdx.y * BM, bn = blockIdx.x * BN;
    const int lrow = tid >> 2;
    const int lk = (tid & 3) << 2;
    float acc[4][4] = {};
    for (int k0 = 0; k0 < DD; k0 += BK) {
        float4 av = *(const float4*)(A + (size_t)(bm + lrow) * DD + k0 + lk);
        float4 bv = *(const float4*)(Bt + (size_t)(bn + lrow) * DD + k0 + lk);
        __syncthreads();
        as[lk + 0][lrow] = av.x; as[lk + 1][lrow] = av.y;
        as[lk + 2][lrow] = av.z; as[lk + 3][lrow] = av.w;
        bs[lk + 0][lrow] = bv.x; bs[lk + 1][lrow] = bv.y;
        bs[lk + 2][lrow] = bv.z; bs[lk + 3][lrow] = bv.w;
        __syncthreads();
#pragma unroll
        for (int kk = 0; kk < BK; ++kk) {
            float a0 = as[kk][ty * 4 + 0], a1 = as[kk][ty * 4 + 1];
            float a2 = as[kk][ty * 4 + 2], a3 = as[kk][ty * 4 + 3];
            float b0 = bs[kk][tx * 4 + 0], b1 = bs[kk][tx * 4 + 1];
            float b2 = bs[kk][tx * 4 + 2], b3 = bs[kk][tx * 4 + 3];
            acc[0][0] += a0 * b0; acc[0][1] += a0 * b1; acc[0][2] += a0 * b2; acc[0][3] += a0 * b3;
            acc[1][0] += a1 * b0; acc[1][1] += a1 * b1; acc[1][2] += a1 * b2; acc[1][3] += a1 * b3;
            acc[2][0] += a2 * b0; acc[2][1] += a2 * b1; acc[2][2] += a2 * b2; acc[2][3] += a2 * b3;
            acc[3][0] += a3 * b0; acc[3][1] += a3 * b1; acc[3][2] += a3 * b2; acc[3][3] += a3 * b3;
        }
    }
#pragma unroll
    for (int i = 0; i < 4; ++i) {
        float4 o = make_float4(acc[i][0], acc[i][1], acc[i][2], acc[i][3]);
        *(float4*)(C + (size_t)(bm + ty * 4 + i) * EE + bn + tx * 4) = o;
    }
}

// ---------------------------------------------------------------------------
// K1b: decb[m] = sum_d dec[m,d] * b_attn[d]   (one wave per row)
// ---------------------------------------------------------------------------
__global__ __launch_bounds__(256) void k_decb(const float* __restrict__ dec,
                                              const float* __restrict__ ba,
                                              float* __restrict__ decb) {
    const int row = blockIdx.x * 4 + (threadIdx.x >> 6);
    const int lane = threadIdx.x & 63;
    const float* x = dec + (size_t)row * DD;
    float s = 0.f;
#pragma unroll
    for (int i = 0; i < 8; ++i) {
        int idx = lane + i * 64;
        s += x[idx] * ba[idx];
    }
#pragma unroll
    for (int off = 32; off >= 1; off >>= 1) s += __shfl_xor(s, off, 64);
    if (lane == 0) decb[row] = s;
}

// ---------------------------------------------------------------------------
// K2: masked_energies[b,t,s] = mask[b,s] ? (sum_e decW[b,t,e]*enc[b,s,e] + decb[b,t])
//                                        : -1e10
//     NT batched GEMM: M=128 (t), N=512 (s), K=1024 (e)
// ---------------------------------------------------------------------------
__global__ __launch_bounds__(256) void k_energy(const float* __restrict__ decW,
                                                const float* __restrict__ enc,
                                                const int* __restrict__ mask,
                                                const float* __restrict__ decb,
                                                float* __restrict__ menerg) {
    const int b = blockIdx.z;
    const float* A = decW + (size_t)b * TT * EE;
    const float* Bt = enc + (size_t)b * SS * EE;
    __shared__ float as[BK][BM + 4];
    __shared__ float bs[BK][BN + 4];
    const int tid = threadIdx.x;
    const int tx = tid & 15, ty = tid >> 4;
    const int bm = blockIdx.y * BM, bn = blockIdx.x * BN;
    const int lrow = tid >> 2;
    const int lk = (tid & 3) << 2;
    float acc[4][4] = {};
    for (int k0 = 0; k0 < EE; k0 += BK) {
        float4 av = *(const float4*)(A + (size_t)(bm + lrow) * EE + k0 + lk);
        float4 bv = *(const float4*)(Bt + (size_t)(bn + lrow) * EE + k0 + lk);
        __syncthreads();
        as[lk + 0][lrow] = av.x; as[lk + 1][lrow] = av.y;
        as[lk + 2][lrow] = av.z; as[lk + 3][lrow] = av.w;
        bs[lk + 0][lrow] = bv.x; bs[lk + 1][lrow] = bv.y;
        bs[lk + 2][lrow] = bv.z; bs[lk + 3][lrow] = bv.w;
        __syncthreads();
#pragma unroll
        for (int kk = 0; kk < BK; ++kk) {
            float a0 = as[kk][ty * 4 + 0], a1 = as[kk][ty * 4 + 1];
            float a2 = as[kk][ty * 4 + 2], a3 = as[kk][ty * 4 + 3];
            float b0 = bs[kk][tx * 4 + 0], b1 = bs[kk][tx * 4 + 1];
            float b2 = bs[kk][tx * 4 + 2], b3 = bs[kk][tx * 4 + 3];
            acc[0][0] += a0 * b0; acc[0][1] += a0 * b1; acc[0][2] += a0 * b2; acc[0][3] += a0 * b3;
            acc[1][0] += a1 * b0; acc[1][1] += a1 * b1; acc[1][2] += a1 * b2; acc[1][3] += a1 * b3;
            acc[2][0] += a2 * b0; acc[2][1] += a2 * b1; acc[2][2] += a2 * b2; acc[2][3] += a2 * b3;
            acc[3][0] += a3 * b0; acc[3][1] += a3 * b1; acc[3][2] += a3 * b2; acc[3][3] += a3 * b3;
        }
    }
    const int* mb = mask + (size_t)b * SS;
    float* Crow = menerg + (size_t)b * TT * SS;
#pragma unroll
    for (int i = 0; i < 4; ++i) {
        const int m = bm + ty * 4 + i;
        const float db = decb[(size_t)b * TT + m];
        float4 o;
        const int n0 = bn + tx * 4;
        o.x = mb[n0 + 0] ? acc[i][0] + db : NEG_INF_F;
        o.y = mb[n0 + 1] ? acc[i][1] + db : NEG_INF_F;
        o.z = mb[n0 + 2] ? acc[i][2] + db : NEG_INF_F;
        o.w = mb[n0 + 3] ? acc[i][3] + db : NEG_INF_F;
        *(float4*)(Crow + (size_t)m * SS + n0) = o;
    }
}

// ---------------------------------------------------------------------------
// K3: softmax over S=512 per row; 128 threads/row, float4 per thread
// ---------------------------------------------------------------------------
__global__ __launch_bounds__(128) void k_softmax(const float* __restrict__ me,
                                                 float* __restrict__ attn) {
    const int row = blockIdx.x;
    const int tid = threadIdx.x;
    const float4 v = ((const float4*)(me + (size_t)row * SS))[tid];
    float m = fmaxf(fmaxf(v.x, v.y), fmaxf(v.z, v.w));
#pragma unroll
    for (int off = 32; off >= 1; off >>= 1) m = fmaxf(m, __shfl_xor(m, off, 64));
    __shared__ float redm[2];
    __shared__ float reds[2];
    const int wv = tid >> 6, lane = tid & 63;
    if (lane == 0) redm[wv] = m;
    __syncthreads();
    m = fmaxf(redm[0], redm[1]);
    float e0 = __expf(v.x - m), e1 = __expf(v.y - m);
    float e2 = __expf(v.z - m), e3 = __expf(v.w - m);
    float s = (e0 + e1) + (e2 + e3);
#pragma unroll
    for (int off = 32; off >= 1; off >>= 1) s += __shfl_xor(s, off, 64);
    if (lane == 0) reds[wv] = s;
    __syncthreads();
    s = reds[0] + reds[1];
    const float inv = 1.0f / s;
    float4 o = make_float4(e0 * inv, e1 * inv, e2 * inv, e3 * inv);
    ((float4*)(attn + (size_t)row * SS))[tid] = o;
}

// ---------------------------------------------------------------------------
// K4: wc[b,t,e] = sum_s attn[b,t,s] * enc[b,s,e]
//     NN batched GEMM: A=[T,S] rowmajor (k along S), B=[S,E] (k rows, n cols)
// ---------------------------------------------------------------------------
__global__ __launch_bounds__(256) void k_ctx(const float* __restrict__ attn,
                                             const float* __restrict__ enc,
                                             float* __restrict__ wc) {
    const int b = blockIdx.z;
    const float* A = attn + (size_t)b * TT * SS;
    const float* Bm = enc + (size_t)b * SS * EE;
    __shared__ float as[BK][BM + 4];
    __shared__ float bs[BK][BN + 4];
    const int tid = threadIdx.x;
    const int tx = tid & 15, ty = tid >> 4;
    const int bm = blockIdx.y * BM, bn = blockIdx.x * BN;
    const int lrow = tid >> 2;      // A: 0..63 row
    const int lk = (tid & 3) << 2;  // A: k quad
    const int lb_k = tid >> 4;      // B: 0..15 k
    const int lb_n = (tid & 15) << 2;
    float acc[4][4] = {};
    for (int k0 = 0; k0 < SS; k0 += BK) {
        float4 av = *(const float4*)(A + (size_t)(bm + lrow) * SS + k0 + lk);
        float4 bv = *(const float4*)(Bm + (size_t)(k0 + lb_k) * EE + bn + lb_n);
        __syncthreads();
        as[lk + 0][lrow] = av.x; as[lk + 1][lrow] = av.y;
        as[lk + 2][lrow] = av.z; as[lk + 3][lrow] = av.w;
        *(float4*)&bs[lb_k][lb_n] = bv;
        __syncthreads();
#pragma unroll
        for (int kk = 0; kk < BK; ++kk) {
            float a0 = as[kk][ty * 4 + 0], a1 = as[kk][ty * 4 + 1];
            float a2 = as[kk][ty * 4 + 2], a3 = as[kk][ty * 4 + 3];
            float b0 = bs[kk][tx * 4 + 0], b1 = bs[kk][tx * 4 + 1];
            float b2 = bs[kk][tx * 4 + 2], b3 = bs[kk][tx * 4 + 3];
            acc[0][0] += a0 * b0; acc[0][1] += a0 * b1; acc[0][2] += a0 * b2; acc[0][3] += a0 * b3;
            acc[1][0] += a1 * b0; acc[1][1] += a1 * b1; acc[1][2] += a1 * b2; acc[1][3] += a1 * b3;
            acc[2][0] += a2 * b0; acc[2][1] += a2 * b1; acc[2][2] += a2 * b2; acc[2][3] += a2 * b3;
            acc[3][0] += a3 * b0; acc[3][1] += a3 * b1; acc[3][2] += a3 * b2; acc[3][3] += a3 * b3;
        }
    }
    float* C = wc + (size_t)b * TT * EE;
#pragma unroll
    for (int i = 0; i < 4; ++i) {
        float4 o = make_float4(acc[i][0], acc[i][1], acc[i][2], acc[i][3]);
        *(float4*)(C + (size_t)(bm + ty * 4 + i) * EE + bn + tx * 4) = o;
    }
}

// ---------------------------------------------------------------------------
// K5: h_tilde[m,n] = tanh( sum_{k<1024} wc[m,k]*Wo[k,n] + sum_{k<512} dec[m,k]*Wo[1024+k,n] )
//     NN GEMM M=8192, N=512, K=1536; A source split at k=1024
// ---------------------------------------------------------------------------
__global__ __launch_bounds__(256) void k_out(const float* __restrict__ wc,
                                             const float* __restrict__ dec,
                                             const float* __restrict__ Wo,
                                             float* __restrict__ ht) {
    __shared__ float as[BK][BM + 4];
    __shared__ float bs[BK][BN + 4];
    const int tid = threadIdx.x;
    const int tx = tid & 15, ty = tid >> 4;
    const int bm = blockIdx.y * BM, bn = blockIdx.x * BN;
    const int lrow = tid >> 2;
    const int lk = (tid & 3) << 2;
    const int lb_k = tid >> 4;
    const int lb_n = (tid & 15) << 2;
    float acc[4][4] = {};
    for (int k0 = 0; k0 < EE + DD; k0 += BK) {
        float4 av;
        if (k0 < EE) {
            av = *(const float4*)(wc + (size_t)(bm + lrow) * EE + k0 + lk);
        } else {
            av = *(const float4*)(dec + (size_t)(bm + lrow) * DD + (k0 - EE) + lk);
        }
        float4 bv = *(const float4*)(Wo + (size_t)(k0 + lb_k) * DD + bn + lb_n);
        __syncthreads();
        as[lk + 0][lrow] = av.x; as[lk + 1][lrow] = av.y;
        as[lk + 2][lrow] = av.z; as[lk + 3][lrow] = av.w;
        *(float4*)&bs[lb_k][lb_n] = bv;
        __syncthreads();
#pragma unroll
        for (int kk = 0; kk < BK; ++kk) {
            float a0 = as[kk][ty * 4 + 0], a1 = as[kk][ty * 4 + 1];
            float a2 = as[kk][ty * 4 + 2], a3 = as[kk][ty * 4 + 3];
            float b0 = bs[kk][tx * 4 + 0], b1 = bs[kk][tx * 4 + 1];
            float b2 = bs[kk][tx * 4 + 2], b3 = bs[kk][tx * 4 + 3];
            acc[0][0] += a0 * b0; acc[0][1] += a0 * b1; acc[0][2] += a0 * b2; acc[0][3] += a0 * b3;
            acc[1][0] += a1 * b0; acc[1][1] += a1 * b1; acc[1][2] += a1 * b2; acc[1][3] += a1 * b3;
            acc[2][0] += a2 * b0; acc[2][1] += a2 * b1; acc[2][2] += a2 * b2; acc[2][3] += a2 * b3;
            acc[3][0] += a3 * b0; acc[3][1] += a3 * b1; acc[3][2] += a3 * b2; acc[3][3] += a3 * b3;
        }
    }
#pragma unroll
    for (int i = 0; i < 4; ++i) {
        float4 o = make_float4(tanhf(acc[i][0]), tanhf(acc[i][1]),
                               tanhf(acc[i][2]), tanhf(acc[i][3]));
        *(float4*)(ht + (size_t)(bm + ty * 4 + i) * DD + bn + tx * 4) = o;
    }
}

// ---------------------------------------------------------------------------
extern "C" void kernel_launch(void* const* d_in, const int* in_sizes, int n_in,
                              void* d_out, int out_size, void* d_ws, size_t ws_size,
                              hipStream_t stream) {
    (void)in_sizes; (void)n_in; (void)out_size; (void)ws_size;
    const float* dec = (const float*)d_in[0];   // [B,T,D]
    const float* enc = (const float*)d_in[1];   // [B,S,E]
    const int* mask = (const int*)d_in[2];      // [B,S]
    const float* Wa = (const float*)d_in[3];    // [E,D]
    const float* ba = (const float*)d_in[4];    // [D]
    const float* Wo = (const float*)d_in[5];    // [E+D,D]

    float* h_tilde = (float*)d_out;                       // [B,T,D]   4,194,304
    float* attn = h_tilde + (size_t)BB * TT * DD;         // [B,T,S]   4,194,304
    float* menerg = attn + (size_t)BB * TT * SS;          // [B,T,S]   4,194,304

    float* decW = (float*)d_ws;                           // [B,T,E] (aliased with wc)
    float* wc = decW;                                     // decW dead after k_energy
    float* decb = decW + (size_t)BB * TT * EE;            // [B*T]

    // K1: decW = dec @ W_attn^T   (M=8192, N=1024, K=512)
    k_decw<<<dim3(EE / BN, (BB * TT) / BM), 256, 0, stream>>>(dec, Wa, decW);
    // K1b: decb = dec . b_attn
    k_decb<<<(BB * TT) / 4, 256, 0, stream>>>(dec, ba, decb);
    // K2: masked energies (batched NT) -> out chunk 2
    k_energy<<<dim3(SS / BN, TT / BM, BB), 256, 0, stream>>>(decW, enc, mask, decb, menerg);
    // K3: softmax -> out chunk 1
    k_softmax<<<BB * TT, 128, 0, stream>>>(menerg, attn);
    // K4: weighted context (batched NN) — overwrites decW region
    k_ctx<<<dim3(EE / BN, TT / BM, BB), 256, 0, stream>>>(attn, enc, wc);
    // K5: h_tilde = tanh([wc|dec] @ W_out) -> out chunk 0
    k_out<<<dim3(DD / BN, (BB * TT) / BM), 256, 0, stream>>>(wc, dec, Wo, h_tilde);
}

// Round 2
// 453.962 us; speedup vs baseline: 1.5725x; 1.5725x over previous
//
#include <hip/hip_runtime.h>
#include <cmath>

// Problem constants
#define BB 64
#define TT 128
#define SS 512
#define EE 1024
#define DDIM 512
#define NEG_INF_F (-1.0e10f)

// MFMA GEMM tiling: block tile 128x64, K-tile 32, 4 waves (2x2), wave tile 64x32
#define BM 128
#define BN 64
#define BK 32
#define LDST 18   // LDS row stride in dwords: 16 data (32 bf16) + 2 pad (72B rows, 8B-aligned, <=2-4 way banks)

typedef __attribute__((ext_vector_type(8))) short bf16x8;
typedef __attribute__((ext_vector_type(4))) float f32x4;

// ---------------------------------------------------------------------------
// fp32 -> bf16 split helpers (hi = rne(f), lo = rne(f - hi)); 2^-18 rel error
// ---------------------------------------------------------------------------
__device__ __forceinline__ unsigned bf16_rne(float f) {
    unsigned u = __float_as_uint(f);
    return (u + 0x7fffu + ((u >> 16) & 1u)) >> 16;
}
__device__ __forceinline__ void split2(float f, unsigned& h, unsigned& l) {
    h = bf16_rne(f);
    float fh = __uint_as_float(h << 16);
    l = bf16_rne(f - fh);
}

// ---------------------------------------------------------------------------
// Stage an NT operand tile (rows x BK, k contiguous in global) into hi/lo LDS.
// src points at element (row0, k0). Packed as u32 = (bf16[k even] | bf16[k odd]<<16).
// ---------------------------------------------------------------------------
template <int ROWS>
__device__ __forceinline__ void stage_nt(unsigned* hi, unsigned* lo,
                                         const float* __restrict__ src, int ld, int tid) {
#pragma unroll
    for (int i = 0; i < ROWS / 32; ++i) {
        int s = tid + 256 * i;
        int r = s >> 3, kq = s & 7;
        float4 v = *(const float4*)(src + (size_t)r * ld + 4 * kq);
        unsigned h0, l0, h1, l1, h2, l2, h3, l3;
        split2(v.x, h0, l0); split2(v.y, h1, l1);
        split2(v.z, h2, l2); split2(v.w, h3, l3);
        uint2 hv = make_uint2(h0 | (h1 << 16), h2 | (h3 << 16));
        uint2 lv = make_uint2(l0 | (l1 << 16), l2 | (l3 << 16));
        *(uint2*)&hi[r * LDST + 2 * kq] = hv;
        *(uint2*)&lo[r * LDST + 2 * kq] = lv;
    }
}

// ---------------------------------------------------------------------------
// Stage a transposed B tile for NN GEMMs: global layout [k=BK rows][n=BN cols]
// (n contiguous), LDS layout rows = n. src points at element (k0, n0), ld = row
// stride of the global matrix. BN=64: 256 units of (2k x 4n), 1 per thread.
// ---------------------------------------------------------------------------
__device__ __forceinline__ void stage_tr(unsigned* hi, unsigned* lo,
                                         const float* __restrict__ src, int ld, int tid) {
    int eq = tid & 15;       // n quad (64/4)
    int sp = tid >> 4;       // k pair (32/2)
    const float* p = src + (size_t)(2 * sp) * ld + 4 * eq;
    float4 va = *(const float4*)p;          // k = 2*sp   (even)
    float4 vb = *(const float4*)(p + ld);   // k = 2*sp+1 (odd)
    float av[4] = {va.x, va.y, va.z, va.w};
    float bv[4] = {vb.x, vb.y, vb.z, vb.w};
#pragma unroll
    for (int c = 0; c < 4; ++c) {
        unsigned ha, la, hb, lb;
        split2(av[c], ha, la);
        split2(bv[c], hb, lb);
        hi[(4 * eq + c) * LDST + sp] = ha | (hb << 16);
        lo[(4 * eq + c) * LDST + sp] = la | (lb << 16);
    }
}

// ---------------------------------------------------------------------------
// Read one 16x16x32 A/B fragment: lane holds [row][k=(lane>>4)*8 + j], j=0..7
// ---------------------------------------------------------------------------
__device__ __forceinline__ bf16x8 read_frag(const unsigned* buf, int row, int q) {
    const unsigned* p = buf + row * LDST + 4 * q;
    uint2 x = *(const uint2*)p;
    uint2 y = *(const uint2*)(p + 2);
    union { unsigned u[4]; bf16x8 s; } f;
    f.u[0] = x.x; f.u[1] = x.y; f.u[2] = y.x; f.u[3] = y.y;
    return f.s;
}

// ---------------------------------------------------------------------------
// Split-bf16 MFMA core: wave (tid>>6) at (wm=(w&1)*64, wn=(w>>1)*32),
// 4x2 tiles of 16x16, 3 MFMAs per tile (Ah*Bh + Ah*Bl + Al*Bh)
// ---------------------------------------------------------------------------
__device__ __forceinline__ void mfma_core(const unsigned* Ah, const unsigned* Al,
                                          const unsigned* Bh, const unsigned* Bl,
                                          f32x4 acc[4][2], int tid) {
    const int lane = tid & 63, w = tid >> 6;
    const int wm = (w & 1) * 64, wn = (w >> 1) * 32;
    const int fr = lane & 15, q = lane >> 4;
    bf16x8 ah[4], al[4];
#pragma unroll
    for (int i = 0; i < 4; ++i) {
        ah[i] = read_frag(Ah, wm + 16 * i + fr, q);
        al[i] = read_frag(Al, wm + 16 * i + fr, q);
    }
#pragma unroll
    for (int j = 0; j < 2; ++j) {
        bf16x8 bh = read_frag(Bh, wn + 16 * j + fr, q);
        bf16x8 bl = read_frag(Bl, wn + 16 * j + fr, q);
#pragma unroll
        for (int i = 0; i < 4; ++i) {
            acc[i][j] = __builtin_amdgcn_mfma_f32_16x16x32_bf16(ah[i], bh, acc[i][j], 0, 0, 0);
            acc[i][j] = __builtin_amdgcn_mfma_f32_16x16x32_bf16(ah[i], bl, acc[i][j], 0, 0, 0);
            acc[i][j] = __builtin_amdgcn_mfma_f32_16x16x32_bf16(al[i], bh, acc[i][j], 0, 0, 0);
        }
    }
}

// ---------------------------------------------------------------------------
// K1: decW[m,e] = sum_d dec[m,d] * W_attn[e,d]   (NT: M=8192, N=1024, K=512)
// ---------------------------------------------------------------------------
__global__ __launch_bounds__(256) void k_decw(const float* __restrict__ A,
                                              const float* __restrict__ Bt,
                                              float* __restrict__ C) {
    __shared__ unsigned Ah[BM * LDST], Al[BM * LDST], Bh[BN * LDST], Bl[BN * LDST];
    const int tid = threadIdx.x;
    const int bm = blockIdx.y * BM, bn = blockIdx.x * BN;
    f32x4 acc[4][2] = {};
    for (int k0 = 0; k0 < DDIM; k0 += BK) {
        stage_nt<BM>(Ah, Al, A + (size_t)bm * DDIM + k0, DDIM, tid);
        stage_nt<BN>(Bh, Bl, Bt + (size_t)bn * DDIM + k0, DDIM, tid);
        __syncthreads();
        mfma_core(Ah, Al, Bh, Bl, acc, tid);
        __syncthreads();
    }
    const int lane = tid & 63, w = tid >> 6;
    const int wm = (w & 1) * 64, wn = (w >> 1) * 32;
    const int fr = lane & 15, q = lane >> 4;
#pragma unroll
    for (int j = 0; j < 2; ++j) {
        const int col = bn + wn + 16 * j + fr;
#pragma unroll
        for (int i = 0; i < 4; ++i)
#pragma unroll
            for (int r = 0; r < 4; ++r) {
                const int row = bm + wm + 16 * i + 4 * q + r;
                C[(size_t)row * EE + col] = acc[i][j][r];
            }
    }
}

// ---------------------------------------------------------------------------
// K1b: decb[m] = sum_d dec[m,d] * b_attn[d]
// ---------------------------------------------------------------------------
__global__ __launch_bounds__(256) void k_decb(const float* __restrict__ dec,
                                              const float* __restrict__ ba,
                                              float* __restrict__ decb) {
    const int row = blockIdx.x * 4 + (threadIdx.x >> 6);
    const int lane = threadIdx.x & 63;
    const float* x = dec + (size_t)row * DDIM;
    float s = 0.f;
#pragma unroll
    for (int i = 0; i < 8; ++i) {
        int idx = lane + i * 64;
        s += x[idx] * ba[idx];
    }
#pragma unroll
    for (int off = 32; off >= 1; off >>= 1) s += __shfl_xor(s, off, 64);
    if (lane == 0) decb[row] = s;
}

// ---------------------------------------------------------------------------
// K2: masked_energies (NT batched: M=T=128, N=S=512, K=E=1024) + bias + mask
// ---------------------------------------------------------------------------
__global__ __launch_bounds__(256) void k_energy(const float* __restrict__ decW,
                                                const float* __restrict__ enc,
                                                const int* __restrict__ mask,
                                                const float* __restrict__ decb,
                                                float* __restrict__ menerg) {
    const int b = blockIdx.z;
    const float* A = decW + (size_t)b * TT * EE;
    const float* Bt = enc + (size_t)b * SS * EE;
    __shared__ unsigned Ah[BM * LDST], Al[BM * LDST], Bh[BN * LDST], Bl[BN * LDST];
    const int tid = threadIdx.x;
    const int bn = blockIdx.x * BN;   // bm = 0 (T == BM)
    f32x4 acc[4][2] = {};
    for (int k0 = 0; k0 < EE; k0 += BK) {
        stage_nt<BM>(Ah, Al, A + (size_t)0 * EE + k0, EE, tid);
        stage_nt<BN>(Bh, Bl, Bt + (size_t)bn * EE + k0, EE, tid);
        __syncthreads();
        mfma_core(Ah, Al, Bh, Bl, acc, tid);
        __syncthreads();
    }
    const int lane = tid & 63, w = tid >> 6;
    const int wm = (w & 1) * 64, wn = (w >> 1) * 32;
    const int fr = lane & 15, q = lane >> 4;
    const int* mb = mask + (size_t)b * SS;
    const float* dbp = decb + (size_t)b * TT;
    float* Crow = menerg + (size_t)b * TT * SS;
    float db[4][4];
#pragma unroll
    for (int i = 0; i < 4; ++i) {
        float4 d4 = *(const float4*)(dbp + wm + 16 * i + 4 * q);
        db[i][0] = d4.x; db[i][1] = d4.y; db[i][2] = d4.z; db[i][3] = d4.w;
    }
#pragma unroll
    for (int j = 0; j < 2; ++j) {
        const int col = bn + wn + 16 * j + fr;
        const int mk = mb[col];
#pragma unroll
        for (int i = 0; i < 4; ++i)
#pragma unroll
            for (int r = 0; r < 4; ++r) {
                const int row = wm + 16 * i + 4 * q + r;
                Crow[(size_t)row * SS + col] = mk ? acc[i][j][r] + db[i][r] : NEG_INF_F;
            }
    }
}

// ---------------------------------------------------------------------------
// K3: softmax over S=512 per row
// ---------------------------------------------------------------------------
__global__ __launch_bounds__(128) void k_softmax(const float* __restrict__ me,
                                                 float* __restrict__ attn) {
    const int row = blockIdx.x;
    const int tid = threadIdx.x;
    const float4 v = ((const float4*)(me + (size_t)row * SS))[tid];
    float m = fmaxf(fmaxf(v.x, v.y), fmaxf(v.z, v.w));
#pragma unroll
    for (int off = 32; off >= 1; off >>= 1) m = fmaxf(m, __shfl_xor(m, off, 64));
    __shared__ float redm[2];
    __shared__ float reds[2];
    const int wv = tid >> 6, lane = tid & 63;
    if (lane == 0) redm[wv] = m;
    __syncthreads();
    m = fmaxf(redm[0], redm[1]);
    float e0 = __expf(v.x - m), e1 = __expf(v.y - m);
    float e2 = __expf(v.z - m), e3 = __expf(v.w - m);
    float s = (e0 + e1) + (e2 + e3);
#pragma unroll
    for (int off = 32; off >= 1; off >>= 1) s += __shfl_xor(s, off, 64);
    if (lane == 0) reds[wv] = s;
    __syncthreads();
    s = reds[0] + reds[1];
    const float inv = 1.0f / s;
    ((float4*)(attn + (size_t)row * SS))[tid] = make_float4(e0 * inv, e1 * inv, e2 * inv, e3 * inv);
}

// ---------------------------------------------------------------------------
// K4: wc[b,t,e] = sum_s attn[b,t,s] * enc[b,s,e]
//     NN batched (M=T=128, N=E=1024, K=S=512): B staged transposed
// ---------------------------------------------------------------------------
__global__ __launch_bounds__(256) void k_ctx(const float* __restrict__ attn,
                                             const float* __restrict__ enc,
                                             float* __restrict__ wc) {
    const int b = blockIdx.z;
    const float* A = attn + (size_t)b * TT * SS;
    const float* Bm = enc + (size_t)b * SS * EE;
    __shared__ unsigned Ah[BM * LDST], Al[BM * LDST], Bh[BN * LDST], Bl[BN * LDST];
    const int tid = threadIdx.x;
    const int bn = blockIdx.x * BN;   // over E
    f32x4 acc[4][2] = {};
    for (int k0 = 0; k0 < SS; k0 += BK) {
        stage_nt<BM>(Ah, Al, A + k0, SS, tid);
        stage_tr(Bh, Bl, Bm + (size_t)k0 * EE + bn, EE, tid);
        __syncthreads();
        mfma_core(Ah, Al, Bh, Bl, acc, tid);
        __syncthreads();
    }
    const int lane = tid & 63, w = tid >> 6;
    const int wm = (w & 1) * 64, wn = (w >> 1) * 32;
    const int fr = lane & 15, q = lane >> 4;
    float* C = wc + (size_t)b * TT * EE;
#pragma unroll
    for (int j = 0; j < 2; ++j) {
        const int col = bn + wn + 16 * j + fr;
#pragma unroll
        for (int i = 0; i < 4; ++i)
#pragma unroll
            for (int r = 0; r < 4; ++r) {
                const int row = wm + 16 * i + 4 * q + r;
                C[(size_t)row * EE + col] = acc[i][j][r];
            }
    }
}

// ---------------------------------------------------------------------------
// K5: h_tilde = tanh([wc | dec] @ W_out)  (NN: M=8192, N=512, K=1536)
//     A switches source at k=1024; B staged transposed
// ---------------------------------------------------------------------------
__global__ __launch_bounds__(256) void k_out(const float* __restrict__ wc,
                                             const float* __restrict__ dec,
                                             const float* __restrict__ Wo,
                                             float* __restrict__ ht) {
    __shared__ unsigned Ah[BM * LDST], Al[BM * LDST], Bh[BN * LDST], Bl[BN * LDST];
    const int tid = threadIdx.x;
    const int bm = blockIdx.y * BM, bn = blockIdx.x * BN;
    f32x4 acc[4][2] = {};
    for (int k0 = 0; k0 < EE + DDIM; k0 += BK) {
        if (k0 < EE)
            stage_nt<BM>(Ah, Al, wc + (size_t)bm * EE + k0, EE, tid);
        else
            stage_nt<BM>(Ah, Al, dec + (size_t)bm * DDIM + (k0 - EE), DDIM, tid);
        stage_tr(Bh, Bl, Wo + (size_t)k0 * DDIM + bn, DDIM, tid);
        __syncthreads();
        mfma_core(Ah, Al, Bh, Bl, acc, tid);
        __syncthreads();
    }
    const int lane = tid & 63, w = tid >> 6;
    const int wm = (w & 1) * 64, wn = (w >> 1) * 32;
    const int fr = lane & 15, q = lane >> 4;
#pragma unroll
    for (int j = 0; j < 2; ++j) {
        const int col = bn + wn + 16 * j + fr;
#pragma unroll
        for (int i = 0; i < 4; ++i)
#pragma unroll
            for (int r = 0; r < 4; ++r) {
                const int row = bm + wm + 16 * i + 4 * q + r;
                ht[(size_t)row * DDIM + col] = tanhf(acc[i][j][r]);
            }
    }
}

// ---------------------------------------------------------------------------
extern "C" void kernel_launch(void* const* d_in, const int* in_sizes, int n_in,
                              void* d_out, int out_size, void* d_ws, size_t ws_size,
                              hipStream_t stream) {
    (void)in_sizes; (void)n_in; (void)out_size; (void)ws_size;
    const float* dec = (const float*)d_in[0];   // [B,T,D]
    const float* enc = (const float*)d_in[1];   // [B,S,E]
    const int* mask = (const int*)d_in[2];      // [B,S]
    const float* Wa = (const float*)d_in[3];    // [E,D]
    const float* ba = (const float*)d_in[4];    // [D]
    const float* Wo = (const float*)d_in[5];    // [E+D,D]

    float* h_tilde = (float*)d_out;                       // [B,T,D]
    float* attn = h_tilde + (size_t)BB * TT * DDIM;       // [B,T,S]
    float* menerg = attn + (size_t)BB * TT * SS;          // [B,T,S]

    float* decW = (float*)d_ws;                           // [B,T,E] fp32 (aliased with wc)
    float* wc = decW;                                     // decW dead after k_energy
    float* decb = decW + (size_t)BB * TT * EE;            // [B*T]

    k_decw<<<dim3(EE / BN, (BB * TT) / BM), 256, 0, stream>>>(dec, Wa, decW);
    k_decb<<<(BB * TT) / 4, 256, 0, stream>>>(dec, ba, decb);
    k_energy<<<dim3(SS / BN, 1, BB), 256, 0, stream>>>(decW, enc, mask, decb, menerg);
    k_softmax<<<BB * TT, 128, 0, stream>>>(menerg, attn);
    k_ctx<<<dim3(EE / BN, 1, BB), 256, 0, stream>>>(attn, enc, wc);
    k_out<<<dim3(DDIM / BN, (BB * TT) / BM), 256, 0, stream>>>(wc, dec, Wo, h_tilde);
}

// Round 3
// 410.483 us; speedup vs baseline: 1.7391x; 1.1059x over previous
//
#include <hip/hip_runtime.h>
#include <cmath>

// Problem constants
#define BB 64
#define TT 128
#define SS 512
#define EE 1024
#define DDIM 512
#define NEG_INF_F (-1.0e10f)

// MFMA tiling: block 128x64, K-tile 32, 4 waves (2x2), wave tile 64x32
#define BM 128
#define BN 64
#define BK 32
#define LDSTP 20   // padded layout row stride (dwords): 80 B rows -> b128-aligned, 2-way banks (free)
#define ROWU 32    // swizzled plane layout row stride in u16 (64 B/row)

typedef unsigned short u16;
typedef __attribute__((ext_vector_type(8))) short bf16x8;
typedef __attribute__((ext_vector_type(4))) float f32x4;

// ---------------------------------------------------------------------------
// fp32 -> bf16 split (hi = rne(f), lo = rne(f - hi)); ~2^-18 rel error
// ---------------------------------------------------------------------------
__device__ __forceinline__ unsigned bf16_rne(float f) {
    unsigned u = __float_as_uint(f);
    return (u + 0x7fffu + ((u >> 16) & 1u)) >> 16;
}
__device__ __forceinline__ void split2(float f, unsigned& h, unsigned& l) {
    h = bf16_rne(f);
    float fh = __uint_as_float(h << 16);
    l = bf16_rne(f - fh);
}

// ---------------------------------------------------------------------------
// glds staging of a bf16 plane tile: ROWS rows x 32 bf16 (64 B/row), with the
// quad-swizzle chunk(q)->slot q^((r>>1)&3). Lane-linear LDS writes (16 B/lane).
// src points at (row0, k0) of a plane with row stride ld (u16 elems).
// ---------------------------------------------------------------------------
template <int ROWS>
__device__ __forceinline__ void stage_glds(u16* lds, const u16* __restrict__ src,
                                           int ld, int tid) {
    const int w = tid >> 6, lane = tid & 63;
    const int rl = lane >> 2, p = lane & 3;
#pragma unroll
    for (int i = 0; i < ROWS / 64; ++i) {
        const int r0 = (w + 4 * i) * 16;
        const int r = r0 + rl;
        const int q = p ^ ((r >> 1) & 3);
        const u16* g = src + (size_t)r * ld + 8 * q;
        __builtin_amdgcn_global_load_lds(
            (const __attribute__((address_space(1))) unsigned*)g,
            (__attribute__((address_space(3))) unsigned*)(lds + r0 * ROWU),
            16, 0, 0);
    }
}

// Read a 16x16x32 fragment from the swizzled plane layout (one ds_read_b128)
__device__ __forceinline__ bf16x8 read_frag_sw(const u16* buf, int row, int q) {
    const int c = q ^ ((row >> 1) & 3);
    return *(const bf16x8*)(buf + row * ROWU + 8 * c);
}

// ---------------------------------------------------------------------------
// VALU staging of an NT fp32 operand (rows x BK, k contiguous) into padded
// hi/lo LDS (u32 = bf16 pair (2k,2k+1)). Used for enc in k_energy.
// ---------------------------------------------------------------------------
template <int ROWS>
__device__ __forceinline__ void stage_nt(unsigned* hi, unsigned* lo,
                                         const float* __restrict__ src, int ld, int tid) {
#pragma unroll
    for (int i = 0; i < ROWS / 32; ++i) {
        int s = tid + 256 * i;
        int r = s >> 3, kq = s & 7;
        float4 v = *(const float4*)(src + (size_t)r * ld + 4 * kq);
        unsigned h0, l0, h1, l1, h2, l2, h3, l3;
        split2(v.x, h0, l0); split2(v.y, h1, l1);
        split2(v.z, h2, l2); split2(v.w, h3, l3);
        *(uint2*)&hi[r * LDSTP + 2 * kq] = make_uint2(h0 | (h1 << 16), h2 | (h3 << 16));
        *(uint2*)&lo[r * LDSTP + 2 * kq] = make_uint2(l0 | (l1 << 16), l2 | (l3 << 16));
    }
}

// ---------------------------------------------------------------------------
// VALU staging of a transposed fp32 B tile for NN GEMM (k_ctx): global
// [BK rows k][BN cols n] -> padded LDS rows = n. src at (k0, n0), ld = row stride.
// ---------------------------------------------------------------------------
__device__ __forceinline__ void stage_tr(unsigned* hi, unsigned* lo,
                                         const float* __restrict__ src, int ld, int tid) {
    int eq = tid & 15;   // n quad
    int sp = tid >> 4;   // k pair
    const float* p = src + (size_t)(2 * sp) * ld + 4 * eq;
    float4 va = *(const float4*)p;
    float4 vb = *(const float4*)(p + ld);
    float av[4] = {va.x, va.y, va.z, va.w};
    float bv[4] = {vb.x, vb.y, vb.z, vb.w};
#pragma unroll
    for (int c = 0; c < 4; ++c) {
        unsigned ha, la, hb, lb;
        split2(av[c], ha, la);
        split2(bv[c], hb, lb);
        hi[(4 * eq + c) * LDSTP + sp] = ha | (hb << 16);
        lo[(4 * eq + c) * LDSTP + sp] = la | (lb << 16);
    }
}

// Read a fragment from the padded layout (aligned b128: 80r+16q bytes)
__device__ __forceinline__ bf16x8 read_frag_pad(const unsigned* buf, int row, int q) {
    return *(const bf16x8*)(buf + row * LDSTP + 4 * q);
}

// ---------------------------------------------------------------------------
// Split-bf16 MFMA cores (3 MFMAs per 16x16 tile: AhBh + AhBl + AlBh)
// ---------------------------------------------------------------------------
__device__ __forceinline__ void mfma_ss(const u16* Ah, const u16* Al,
                                        const u16* Bh, const u16* Bl,
                                        f32x4 acc[4][2], int tid) {
    const int lane = tid & 63, w = tid >> 6;
    const int wm = (w & 1) * 64, wn = (w >> 1) * 32;
    const int fr = lane & 15, q = lane >> 4;
    bf16x8 ah[4], al[4];
#pragma unroll
    for (int i = 0; i < 4; ++i) {
        ah[i] = read_frag_sw(Ah, wm + 16 * i + fr, q);
        al[i] = read_frag_sw(Al, wm + 16 * i + fr, q);
    }
#pragma unroll
    for (int j = 0; j < 2; ++j) {
        bf16x8 bh = read_frag_sw(Bh, wn + 16 * j + fr, q);
        bf16x8 bl = read_frag_sw(Bl, wn + 16 * j + fr, q);
#pragma unroll
        for (int i = 0; i < 4; ++i) {
            acc[i][j] = __builtin_amdgcn_mfma_f32_16x16x32_bf16(ah[i], bh, acc[i][j], 0, 0, 0);
            acc[i][j] = __builtin_amdgcn_mfma_f32_16x16x32_bf16(ah[i], bl, acc[i][j], 0, 0, 0);
            acc[i][j] = __builtin_amdgcn_mfma_f32_16x16x32_bf16(al[i], bh, acc[i][j], 0, 0, 0);
        }
    }
}

__device__ __forceinline__ void mfma_sp(const u16* Ah, const u16* Al,
                                        const unsigned* Bh, const unsigned* Bl,
                                        f32x4 acc[4][2], int tid) {
    const int lane = tid & 63, w = tid >> 6;
    const int wm = (w & 1) * 64, wn = (w >> 1) * 32;
    const int fr = lane & 15, q = lane >> 4;
    bf16x8 ah[4], al[4];
#pragma unroll
    for (int i = 0; i < 4; ++i) {
        ah[i] = read_frag_sw(Ah, wm + 16 * i + fr, q);
        al[i] = read_frag_sw(Al, wm + 16 * i + fr, q);
    }
#pragma unroll
    for (int j = 0; j < 2; ++j) {
        bf16x8 bh = read_frag_pad(Bh, wn + 16 * j + fr, q);
        bf16x8 bl = read_frag_pad(Bl, wn + 16 * j + fr, q);
#pragma unroll
        for (int i = 0; i < 4; ++i) {
            acc[i][j] = __builtin_amdgcn_mfma_f32_16x16x32_bf16(ah[i], bh, acc[i][j], 0, 0, 0);
            acc[i][j] = __builtin_amdgcn_mfma_f32_16x16x32_bf16(ah[i], bl, acc[i][j], 0, 0, 0);
            acc[i][j] = __builtin_amdgcn_mfma_f32_16x16x32_bf16(al[i], bh, acc[i][j], 0, 0, 0);
        }
    }
}

// ---------------------------------------------------------------------------
// Convert kernels
// ---------------------------------------------------------------------------
__global__ __launch_bounds__(256) void k_conv(const float* __restrict__ src,
                                              u16* __restrict__ hi, u16* __restrict__ lo) {
    const int i = blockIdx.x * 256 + threadIdx.x;
    float4 v = ((const float4*)src)[i];
    unsigned h0, l0, h1, l1, h2, l2, h3, l3;
    split2(v.x, h0, l0); split2(v.y, h1, l1);
    split2(v.z, h2, l2); split2(v.w, h3, l3);
    ((ushort4*)hi)[i] = make_ushort4((u16)h0, (u16)h1, (u16)h2, (u16)h3);
    ((ushort4*)lo)[i] = make_ushort4((u16)l0, (u16)l1, (u16)l2, (u16)l3);
}

// Wo [1536,512] -> WoT planes [512,1536]
__global__ __launch_bounds__(256) void k_wot(const float* __restrict__ Wo,
                                             u16* __restrict__ thi, u16* __restrict__ tlo) {
    __shared__ float t[64][65];
    const int tid = threadIdx.x;
    const int r0 = blockIdx.x * 64;  // Wo row tile (k)
    const int c0 = blockIdx.y * 64;  // Wo col tile (n)
    const int rr = tid >> 4, cc = tid & 15;
#pragma unroll
    for (int i = 0; i < 4; ++i) {
        float4 v = *(const float4*)(Wo + (size_t)(r0 + rr + 16 * i) * DDIM + c0 + 4 * cc);
        t[rr + 16 * i][4 * cc + 0] = v.x;
        t[rr + 16 * i][4 * cc + 1] = v.y;
        t[rr + 16 * i][4 * cc + 2] = v.z;
        t[rr + 16 * i][4 * cc + 3] = v.w;
    }
    __syncthreads();
#pragma unroll
    for (int i = 0; i < 4; ++i) {
        const int oc = rr + 16 * i;  // WoT row (= Wo col)
        unsigned h0, l0, h1, l1, h2, l2, h3, l3;
        split2(t[4 * cc + 0][oc], h0, l0);
        split2(t[4 * cc + 1][oc], h1, l1);
        split2(t[4 * cc + 2][oc], h2, l2);
        split2(t[4 * cc + 3][oc], h3, l3);
        size_t off = (size_t)(c0 + oc) * (EE + DDIM) + r0 + 4 * cc;
        *(ushort4*)(thi + off) = make_ushort4((u16)h0, (u16)h1, (u16)h2, (u16)h3);
        *(ushort4*)(tlo + off) = make_ushort4((u16)l0, (u16)l1, (u16)l2, (u16)l3);
    }
}

// ---------------------------------------------------------------------------
// K1: decW = dec @ W_attn^T (NT, M=8192, N=1024, K=512) -> hi/lo planes
// ---------------------------------------------------------------------------
__global__ __launch_bounds__(256) void k_decw(const u16* __restrict__ Ahp, const u16* __restrict__ Alp,
                                              const u16* __restrict__ Bhp, const u16* __restrict__ Blp,
                                              u16* __restrict__ Chi, u16* __restrict__ Clo) {
    __shared__ u16 Ah[BM * ROWU], Al[BM * ROWU], Bh[BN * ROWU], Bl[BN * ROWU];
    const int tid = threadIdx.x;
    const int bm = blockIdx.x * BM, bn = blockIdx.y * BN;  // x = m for B-tile L2 reuse
    f32x4 acc[4][2] = {};
    for (int k0 = 0; k0 < DDIM; k0 += BK) {
        __syncthreads();
        stage_glds<BM>(Ah, Ahp + (size_t)bm * DDIM + k0, DDIM, tid);
        stage_glds<BM>(Al, Alp + (size_t)bm * DDIM + k0, DDIM, tid);
        stage_glds<BN>(Bh, Bhp + (size_t)bn * DDIM + k0, DDIM, tid);
        stage_glds<BN>(Bl, Blp + (size_t)bn * DDIM + k0, DDIM, tid);
        __builtin_amdgcn_s_waitcnt(0);
        __syncthreads();
        mfma_ss(Ah, Al, Bh, Bl, acc, tid);
    }
    const int lane = tid & 63, w = tid >> 6;
    const int wm = (w & 1) * 64, wn = (w >> 1) * 32;
    const int fr = lane & 15, q = lane >> 4;
#pragma unroll
    for (int j = 0; j < 2; ++j) {
        const int col = bn + wn + 16 * j + fr;
#pragma unroll
        for (int i = 0; i < 4; ++i)
#pragma unroll
            for (int r = 0; r < 4; ++r) {
                const int row = bm + wm + 16 * i + 4 * q + r;
                unsigned h, l;
                split2(acc[i][j][r], h, l);
                Chi[(size_t)row * EE + col] = (u16)h;
                Clo[(size_t)row * EE + col] = (u16)l;
            }
    }
}

// ---------------------------------------------------------------------------
// K1b: decb[m] = dec[m,:] . b_attn
// ---------------------------------------------------------------------------
__global__ __launch_bounds__(256) void k_decb(const float* __restrict__ dec,
                                              const float* __restrict__ ba,
                                              float* __restrict__ decb) {
    const int row = blockIdx.x * 4 + (threadIdx.x >> 6);
    const int lane = threadIdx.x & 63;
    const float* x = dec + (size_t)row * DDIM;
    float s = 0.f;
#pragma unroll
    for (int i = 0; i < 8; ++i) {
        int idx = lane + i * 64;
        s += x[idx] * ba[idx];
    }
#pragma unroll
    for (int off = 32; off >= 1; off >>= 1) s += __shfl_xor(s, off, 64);
    if (lane == 0) decb[row] = s;
}

// ---------------------------------------------------------------------------
// K2: masked energies (NT batched, M=T=128, N=S, K=E) + bias + mask
// ---------------------------------------------------------------------------
__global__ __launch_bounds__(256) void k_energy(const u16* __restrict__ Ahp, const u16* __restrict__ Alp,
                                                const float* __restrict__ enc,
                                                const int* __restrict__ mask,
                                                const float* __restrict__ decb,
                                                float* __restrict__ menerg) {
    const int b = blockIdx.z;
    const int bn = blockIdx.x * BN;
    __shared__ u16 Ah[BM * ROWU], Al[BM * ROWU];
    __shared__ unsigned Bh[BN * LDSTP], Bl[BN * LDSTP];
    const int tid = threadIdx.x;
    const u16* Abh = Ahp + (size_t)b * TT * EE;
    const u16* Abl = Alp + (size_t)b * TT * EE;
    const float* Bt = enc + (size_t)b * SS * EE + (size_t)bn * EE;
    f32x4 acc[4][2] = {};
    for (int k0 = 0; k0 < EE; k0 += BK) {
        __syncthreads();
        stage_glds<BM>(Ah, Abh + k0, EE, tid);
        stage_glds<BM>(Al, Abl + k0, EE, tid);
        stage_nt<BN>(Bh, Bl, Bt + k0, EE, tid);
        __builtin_amdgcn_s_waitcnt(0);
        __syncthreads();
        mfma_sp(Ah, Al, Bh, Bl, acc, tid);
    }
    const int lane = tid & 63, w = tid >> 6;
    const int wm = (w & 1) * 64, wn = (w >> 1) * 32;
    const int fr = lane & 15, q = lane >> 4;
    const int* mb = mask + (size_t)b * SS;
    const float* dbp = decb + (size_t)b * TT;
    float* Crow = menerg + (size_t)b * TT * SS;
    float db[4][4];
#pragma unroll
    for (int i = 0; i < 4; ++i) {
        float4 d4 = *(const float4*)(dbp + wm + 16 * i + 4 * q);
        db[i][0] = d4.x; db[i][1] = d4.y; db[i][2] = d4.z; db[i][3] = d4.w;
    }
#pragma unroll
    for (int j = 0; j < 2; ++j) {
        const int col = bn + wn + 16 * j + fr;
        const int mk = mb[col];
#pragma unroll
        for (int i = 0; i < 4; ++i)
#pragma unroll
            for (int r = 0; r < 4; ++r) {
                const int row = wm + 16 * i + 4 * q + r;
                Crow[(size_t)row * SS + col] = mk ? acc[i][j][r] + db[i][r] : NEG_INF_F;
            }
    }
}

// ---------------------------------------------------------------------------
// K3: softmax over S=512 -> attn fp32 (output) + attn hi/lo planes
// ---------------------------------------------------------------------------
__global__ __launch_bounds__(128) void k_softmax(const float* __restrict__ me,
                                                 float* __restrict__ attn,
                                                 u16* __restrict__ ahi,
                                                 u16* __restrict__ alo) {
    const int row = blockIdx.x;
    const int tid = threadIdx.x;
    const float4 v = ((const float4*)(me + (size_t)row * SS))[tid];
    float m = fmaxf(fmaxf(v.x, v.y), fmaxf(v.z, v.w));
#pragma unroll
    for (int off = 32; off >= 1; off >>= 1) m = fmaxf(m, __shfl_xor(m, off, 64));
    __shared__ float redm[2];
    __shared__ float reds[2];
    const int wv = tid >> 6, lane = tid & 63;
    if (lane == 0) redm[wv] = m;
    __syncthreads();
    m = fmaxf(redm[0], redm[1]);
    float e0 = __expf(v.x - m), e1 = __expf(v.y - m);
    float e2 = __expf(v.z - m), e3 = __expf(v.w - m);
    float s = (e0 + e1) + (e2 + e3);
#pragma unroll
    for (int off = 32; off >= 1; off >>= 1) s += __shfl_xor(s, off, 64);
    if (lane == 0) reds[wv] = s;
    __syncthreads();
    s = reds[0] + reds[1];
    const float inv = 1.0f / s;
    float o0 = e0 * inv, o1 = e1 * inv, o2 = e2 * inv, o3 = e3 * inv;
    ((float4*)(attn + (size_t)row * SS))[tid] = make_float4(o0, o1, o2, o3);
    unsigned h0, l0, h1, l1, h2, l2, h3, l3;
    split2(o0, h0, l0); split2(o1, h1, l1); split2(o2, h2, l2); split2(o3, h3, l3);
    ((ushort4*)(ahi + (size_t)row * SS))[tid] = make_ushort4((u16)h0, (u16)h1, (u16)h2, (u16)h3);
    ((ushort4*)(alo + (size_t)row * SS))[tid] = make_ushort4((u16)l0, (u16)l1, (u16)l2, (u16)l3);
}

// ---------------------------------------------------------------------------
// K4: wc = attn @ enc (NN batched, M=T, N=E, K=S) -> wc hi/lo planes
// ---------------------------------------------------------------------------
__global__ __launch_bounds__(256) void k_ctx(const u16* __restrict__ Ahp, const u16* __restrict__ Alp,
                                             const float* __restrict__ enc,
                                             u16* __restrict__ Chi, u16* __restrict__ Clo) {
    const int b = blockIdx.z;
    const int bn = blockIdx.x * BN;  // over E
    __shared__ u16 Ah[BM * ROWU], Al[BM * ROWU];
    __shared__ unsigned Bh[BN * LDSTP], Bl[BN * LDSTP];
    const int tid = threadIdx.x;
    const u16* Abh = Ahp + (size_t)b * TT * SS;
    const u16* Abl = Alp + (size_t)b * TT * SS;
    const float* Bm = enc + (size_t)b * SS * EE + bn;
    f32x4 acc[4][2] = {};
    for (int k0 = 0; k0 < SS; k0 += BK) {
        __syncthreads();
        stage_glds<BM>(Ah, Abh + k0, SS, tid);
        stage_glds<BM>(Al, Abl + k0, SS, tid);
        stage_tr(Bh, Bl, Bm + (size_t)k0 * EE, EE, tid);
        __builtin_amdgcn_s_waitcnt(0);
        __syncthreads();
        mfma_sp(Ah, Al, Bh, Bl, acc, tid);
    }
    const int lane = tid & 63, w = tid >> 6;
    const int wm = (w & 1) * 64, wn = (w >> 1) * 32;
    const int fr = lane & 15, q = lane >> 4;
    u16* Ch = Chi + (size_t)b * TT * EE;
    u16* Cl = Clo + (size_t)b * TT * EE;
#pragma unroll
    for (int j = 0; j < 2; ++j) {
        const int col = bn + wn + 16 * j + fr;
#pragma unroll
        for (int i = 0; i < 4; ++i)
#pragma unroll
            for (int r = 0; r < 4; ++r) {
                const int row = wm + 16 * i + 4 * q + r;
                unsigned h, l;
                split2(acc[i][j][r], h, l);
                Ch[(size_t)row * EE + col] = (u16)h;
                Cl[(size_t)row * EE + col] = (u16)l;
            }
    }
}

// ---------------------------------------------------------------------------
// K5: h_tilde = tanh([wc | dec] @ W_out) via WoT planes (NT, M=8192, N=512, K=1536)
// ---------------------------------------------------------------------------
__global__ __launch_bounds__(256) void k_out(const u16* __restrict__ wch, const u16* __restrict__ wcl,
                                             const u16* __restrict__ dech, const u16* __restrict__ decl,
                                             const u16* __restrict__ woth, const u16* __restrict__ wotl,
                                             float* __restrict__ ht) {
    __shared__ u16 Ah[BM * ROWU], Al[BM * ROWU], Bh[BN * ROWU], Bl[BN * ROWU];
    const int tid = threadIdx.x;
    const int bm = blockIdx.x * BM, bn = blockIdx.y * BN;  // x = m for B-tile reuse
    f32x4 acc[4][2] = {};
    for (int k0 = 0; k0 < EE + DDIM; k0 += BK) {
        const u16 *ah, *al;
        int ld;
        if (k0 < EE) {
            ah = wch + (size_t)bm * EE + k0;
            al = wcl + (size_t)bm * EE + k0;
            ld = EE;
        } else {
            ah = dech + (size_t)bm * DDIM + (k0 - EE);
            al = decl + (size_t)bm * DDIM + (k0 - EE);
            ld = DDIM;
        }
        __syncthreads();
        stage_glds<BM>(Ah, ah, ld, tid);
        stage_glds<BM>(Al, al, ld, tid);
        stage_glds<BN>(Bh, woth + (size_t)bn * (EE + DDIM) + k0, EE + DDIM, tid);
        stage_glds<BN>(Bl, wotl + (size_t)bn * (EE + DDIM) + k0, EE + DDIM, tid);
        __builtin_amdgcn_s_waitcnt(0);
        __syncthreads();
        mfma_ss(Ah, Al, Bh, Bl, acc, tid);
    }
    const int lane = tid & 63, w = tid >> 6;
    const int wm = (w & 1) * 64, wn = (w >> 1) * 32;
    const int fr = lane & 15, q = lane >> 4;
#pragma unroll
    for (int j = 0; j < 2; ++j) {
        const int col = bn + wn + 16 * j + fr;
#pragma unroll
        for (int i = 0; i < 4; ++i)
#pragma unroll
            for (int r = 0; r < 4; ++r) {
                const int row = bm + wm + 16 * i + 4 * q + r;
                ht[(size_t)row * DDIM + col] = tanhf(acc[i][j][r]);
            }
    }
}

// ---------------------------------------------------------------------------
extern "C" void kernel_launch(void* const* d_in, const int* in_sizes, int n_in,
                              void* d_out, int out_size, void* d_ws, size_t ws_size,
                              hipStream_t stream) {
    (void)in_sizes; (void)n_in; (void)out_size; (void)ws_size;
    const float* dec = (const float*)d_in[0];
    const float* enc = (const float*)d_in[1];
    const int* mask = (const int*)d_in[2];
    const float* Wa = (const float*)d_in[3];
    const float* ba = (const float*)d_in[4];
    const float* Wo = (const float*)d_in[5];

    float* h_tilde = (float*)d_out;
    float* attn = h_tilde + (size_t)BB * TT * DDIM;
    float* menerg = attn + (size_t)BB * TT * SS;

    // Workspace layout (bytes), total ~72.4 MB
    char* ws = (char*)d_ws;
    u16* decW_hi = (u16*)(ws);                       // 8192x1024 u16 = 16.78 MB
    u16* decW_lo = (u16*)(ws + 16777216);
    u16* dec_hi  = (u16*)(ws + 33554432);            // 8192x512
    u16* dec_lo  = (u16*)(ws + 41943040);
    u16* attn_hi = (u16*)(ws + 50331648);            // 8192x512
    u16* attn_lo = (u16*)(ws + 58720256);
    u16* wa_hi   = (u16*)(ws + 67108864);            // 1024x512
    u16* wa_lo   = (u16*)(ws + 68157440);
    u16* wot_hi  = (u16*)(ws + 69206016);            // 512x1536
    u16* wot_lo  = (u16*)(ws + 70778880);
    float* decb  = (float*)(ws + 72351744);          // 8192 f32
    // wc planes alias decW planes (decW dead after k_energy)
    u16* wc_hi = decW_hi;
    u16* wc_lo = decW_lo;

    k_conv<<<(BB * TT * DDIM) / 4 / 256, 256, 0, stream>>>(dec, dec_hi, dec_lo);
    k_conv<<<(EE * DDIM) / 4 / 256, 256, 0, stream>>>(Wa, wa_hi, wa_lo);
    k_wot<<<dim3((EE + DDIM) / 64, DDIM / 64), 256, 0, stream>>>(Wo, wot_hi, wot_lo);
    k_decb<<<(BB * TT) / 4, 256, 0, stream>>>(dec, ba, decb);
    k_decw<<<dim3((BB * TT) / BM, EE / BN), 256, 0, stream>>>(dec_hi, dec_lo, wa_hi, wa_lo,
                                                              decW_hi, decW_lo);
    k_energy<<<dim3(SS / BN, 1, BB), 256, 0, stream>>>(decW_hi, decW_lo, enc, mask, decb, menerg);
    k_softmax<<<BB * TT, 128, 0, stream>>>(menerg, attn, attn_hi, attn_lo);
    k_ctx<<<dim3(EE / BN, 1, BB), 256, 0, stream>>>(attn_hi, attn_lo, enc, wc_hi, wc_lo);
    k_out<<<dim3((BB * TT) / BM, DDIM / BN), 256, 0, stream>>>(wc_hi, wc_lo, dec_hi, dec_lo,
                                                               wot_hi, wot_lo, h_tilde);
}